// Round 1
// baseline (2892.618 us; speedup 1.0000x reference)
//
#include <hip/hip_runtime.h>
#include <math.h>

#define N_NODES 100000
#define N_EDGES 3200000
#define F_IN    128
#define F_HID   32
#define N_CLS   10

// ---------------- Kernel A: a = x@W1+b1, b = x@W2, c = x@W3+b3 ----------------
// block 256 = 64 nodes x 4 parts; part p computes features [8p, 8p+8) of all 3 mats.
__global__ __launch_bounds__(256) void gemm3_kernel(
    const float* __restrict__ x,
    const float* __restrict__ W1, const float* __restrict__ b1,
    const float* __restrict__ W2,
    const float* __restrict__ W3, const float* __restrict__ b3,
    float* __restrict__ a, float* __restrict__ b, float* __restrict__ c)
{
    __shared__ float Wl[3][F_IN][F_HID];   // 48 KB
    const int tid = threadIdx.x;

    // cooperative load of the three weight matrices (3*128*32 = 3072 float4)
    float4* Wlv = (float4*)&Wl[0][0][0];
    for (int i = tid; i < 3 * F_IN * F_HID / 4; i += 256) {
        int m = i >> 10;          // 1024 float4 per matrix
        int r = i & 1023;
        const float4* srcp = (m == 0) ? (const float4*)W1
                           : (m == 1) ? (const float4*)W2
                                      : (const float4*)W3;
        Wlv[i] = srcp[r];
    }
    __syncthreads();

    const int node = blockIdx.x * 64 + (tid >> 2);
    const int p    = tid & 3;
    if (node >= N_NODES) return;

    float acc[3][8];
#pragma unroll
    for (int m = 0; m < 3; ++m)
#pragma unroll
        for (int i = 0; i < 8; ++i) acc[m][i] = 0.f;

    const float4* xrow = (const float4*)(x + (size_t)node * F_IN);
#pragma unroll 4
    for (int kk = 0; kk < F_IN / 4; ++kk) {
        float4 xv = xrow[kk];
#pragma unroll
        for (int j = 0; j < 4; ++j) {
            const int k = 4 * kk + j;
            const float xk = (&xv.x)[j];
#pragma unroll
            for (int m = 0; m < 3; ++m) {
                float4 wa = *(const float4*)&Wl[m][k][p * 8];
                float4 wb = *(const float4*)&Wl[m][k][p * 8 + 4];
                acc[m][0] += xk * wa.x; acc[m][1] += xk * wa.y;
                acc[m][2] += xk * wa.z; acc[m][3] += xk * wa.w;
                acc[m][4] += xk * wb.x; acc[m][5] += xk * wb.y;
                acc[m][6] += xk * wb.z; acc[m][7] += xk * wb.w;
            }
        }
    }

#pragma unroll
    for (int i = 0; i < 8; ++i) {
        acc[0][i] += b1[p * 8 + i];
        acc[2][i] += b3[p * 8 + i];
    }

    const size_t base = (size_t)node * F_HID + p * 8;
    *(float4*)&a[base]     = make_float4(acc[0][0], acc[0][1], acc[0][2], acc[0][3]);
    *(float4*)&a[base + 4] = make_float4(acc[0][4], acc[0][5], acc[0][6], acc[0][7]);
    *(float4*)&b[base]     = make_float4(acc[1][0], acc[1][1], acc[1][2], acc[1][3]);
    *(float4*)&b[base + 4] = make_float4(acc[1][4], acc[1][5], acc[1][6], acc[1][7]);
    *(float4*)&c[base]     = make_float4(acc[2][0], acc[2][1], acc[2][2], acc[2][3]);
    *(float4*)&c[base + 4] = make_float4(acc[2][4], acc[2][5], acc[2][6], acc[2][7]);
}

// ---------------- Kernel B: edge scatter ----------------
// c[dst] -= ew * b[src]  (32 feats), degw[dst] += ew
// 4 threads per edge, 8 features per thread.
__global__ __launch_bounds__(256) void edge_scatter_kernel(
    const int* __restrict__ ei,     // [2*E], row0 = src, row1 = dst
    const float* __restrict__ ea,   // [E]
    const float* __restrict__ b,
    float* __restrict__ c, float* __restrict__ degw)
{
    const long long t = (long long)blockIdx.x * 256 + threadIdx.x;
    const int e = (int)(t >> 2);
    const int p = (int)(t & 3);
    if (e >= N_EDGES) return;

    const int src = ei[e];
    const int dst = ei[N_EDGES + e];
    const float ew = ea[e];

    const float4* bs = (const float4*)(b + (size_t)src * F_HID) + p * 2;
    float4 v0 = bs[0], v1 = bs[1];

    float* cd = c + (size_t)dst * F_HID + p * 8;
    unsafeAtomicAdd(&cd[0], -ew * v0.x);
    unsafeAtomicAdd(&cd[1], -ew * v0.y);
    unsafeAtomicAdd(&cd[2], -ew * v0.z);
    unsafeAtomicAdd(&cd[3], -ew * v0.w);
    unsafeAtomicAdd(&cd[4], -ew * v1.x);
    unsafeAtomicAdd(&cd[5], -ew * v1.y);
    unsafeAtomicAdd(&cd[6], -ew * v1.z);
    unsafeAtomicAdd(&cd[7], -ew * v1.w);
    if (p == 0) unsafeAtomicAdd(&degw[dst], ew);
}

// ---------------- Kernel C: finalize ----------------
// h = elu(c + degw*a); logits = h @ fc_w^T + fc_b; out = log_softmax(logits)
__global__ __launch_bounds__(256) void finalize_kernel(
    const float* __restrict__ a, const float* __restrict__ c,
    const float* __restrict__ degw,
    const float* __restrict__ fc_w, const float* __restrict__ fc_b,
    float* __restrict__ out)
{
    __shared__ float Wf[N_CLS][F_HID];
    __shared__ float Bf[N_CLS];
    const int tid = threadIdx.x;
    for (int i = tid; i < N_CLS * F_HID; i += 256)
        ((float*)Wf)[i] = fc_w[i];
    if (tid < N_CLS) Bf[tid] = fc_b[tid];
    __syncthreads();

    const int n = blockIdx.x * 256 + tid;
    if (n >= N_NODES) return;

    const float dw = degw[n];
    const float4* av = (const float4*)(a + (size_t)n * F_HID);
    const float4* cv = (const float4*)(c + (size_t)n * F_HID);

    float h[F_HID];
#pragma unroll
    for (int i = 0; i < F_HID / 4; ++i) {
        float4 A = av[i], C = cv[i];
        float t0 = C.x + dw * A.x;
        float t1 = C.y + dw * A.y;
        float t2 = C.z + dw * A.z;
        float t3 = C.w + dw * A.w;
        h[4 * i + 0] = t0 > 0.f ? t0 : expm1f(t0);
        h[4 * i + 1] = t1 > 0.f ? t1 : expm1f(t1);
        h[4 * i + 2] = t2 > 0.f ? t2 : expm1f(t2);
        h[4 * i + 3] = t3 > 0.f ? t3 : expm1f(t3);
    }

    float logits[N_CLS];
    float mx = -1e30f;
#pragma unroll
    for (int j = 0; j < N_CLS; ++j) {
        float s = Bf[j];
#pragma unroll
        for (int f = 0; f < F_HID; ++f) s += h[f] * Wf[j][f];
        logits[j] = s;
        mx = fmaxf(mx, s);
    }
    float sum = 0.f;
#pragma unroll
    for (int j = 0; j < N_CLS; ++j) sum += expf(logits[j] - mx);
    const float lse = mx + logf(sum);

    float* o = out + (size_t)n * N_CLS;
#pragma unroll
    for (int j = 0; j < N_CLS; ++j) o[j] = logits[j] - lse;
}

extern "C" void kernel_launch(void* const* d_in, const int* in_sizes, int n_in,
                              void* d_out, int out_size, void* d_ws, size_t ws_size,
                              hipStream_t stream) {
    const float* x   = (const float*)d_in[0];
    const int*   ei  = (const int*)d_in[1];
    const float* ea  = (const float*)d_in[2];
    const float* W1  = (const float*)d_in[3];
    const float* b1  = (const float*)d_in[4];
    const float* W2  = (const float*)d_in[5];
    const float* W3  = (const float*)d_in[6];
    const float* b3  = (const float*)d_in[7];
    const float* fcw = (const float*)d_in[8];
    const float* fcb = (const float*)d_in[9];
    float* out = (float*)d_out;

    float* a    = (float*)d_ws;
    float* b    = a + (size_t)N_NODES * F_HID;
    float* c    = b + (size_t)N_NODES * F_HID;
    float* degw = c + (size_t)N_NODES * F_HID;

    hipMemsetAsync(degw, 0, N_NODES * sizeof(float), stream);

    gemm3_kernel<<<(N_NODES + 63) / 64, 256, 0, stream>>>(
        x, W1, b1, W2, W3, b3, a, b, c);

    edge_scatter_kernel<<<(int)(((long long)N_EDGES * 4 + 255) / 256), 256, 0, stream>>>(
        ei, ea, b, c, degw);

    finalize_kernel<<<(N_NODES + 255) / 256, 256, 0, stream>>>(
        a, c, degw, fcw, fcb, out);
}

// Round 2
// 533.836 us; speedup vs baseline: 5.4186x; 5.4186x over previous
//
#include <hip/hip_runtime.h>
#include <math.h>

#define N_NODES 100000
#define N_EDGES 3200000
#define F_IN    128
#define F_HID   32
#define N_CLS   10

#define SCAN_CHUNK 2048                       // elements per scan block
#define NSCAN ((N_NODES + SCAN_CHUNK - 1) / SCAN_CHUNK)   // 49

// ---------------- Kernel A: a = x@W1+b1, b = x@W2, c = x@W3+b3 ----------------
__global__ __launch_bounds__(256) void gemm3_kernel(
    const float* __restrict__ x,
    const float* __restrict__ W1, const float* __restrict__ b1,
    const float* __restrict__ W2,
    const float* __restrict__ W3, const float* __restrict__ b3,
    float* __restrict__ a, float* __restrict__ b, float* __restrict__ c)
{
    __shared__ float Wl[3][F_IN][F_HID];   // 48 KB
    const int tid = threadIdx.x;

    float4* Wlv = (float4*)&Wl[0][0][0];
    for (int i = tid; i < 3 * F_IN * F_HID / 4; i += 256) {
        int m = i >> 10;
        int r = i & 1023;
        const float4* srcp = (m == 0) ? (const float4*)W1
                           : (m == 1) ? (const float4*)W2
                                      : (const float4*)W3;
        Wlv[i] = srcp[r];
    }
    __syncthreads();

    const int node = blockIdx.x * 64 + (tid >> 2);
    const int p    = tid & 3;
    if (node >= N_NODES) return;

    float acc[3][8];
#pragma unroll
    for (int m = 0; m < 3; ++m)
#pragma unroll
        for (int i = 0; i < 8; ++i) acc[m][i] = 0.f;

    const float4* xrow = (const float4*)(x + (size_t)node * F_IN);
#pragma unroll 4
    for (int kk = 0; kk < F_IN / 4; ++kk) {
        float4 xv = xrow[kk];
#pragma unroll
        for (int j = 0; j < 4; ++j) {
            const int k = 4 * kk + j;
            const float xk = (&xv.x)[j];
#pragma unroll
            for (int m = 0; m < 3; ++m) {
                float4 wa = *(const float4*)&Wl[m][k][p * 8];
                float4 wb = *(const float4*)&Wl[m][k][p * 8 + 4];
                acc[m][0] += xk * wa.x; acc[m][1] += xk * wa.y;
                acc[m][2] += xk * wa.z; acc[m][3] += xk * wa.w;
                acc[m][4] += xk * wb.x; acc[m][5] += xk * wb.y;
                acc[m][6] += xk * wb.z; acc[m][7] += xk * wb.w;
            }
        }
    }

#pragma unroll
    for (int i = 0; i < 8; ++i) {
        acc[0][i] += b1[p * 8 + i];
        acc[2][i] += b3[p * 8 + i];
    }

    const size_t base = (size_t)node * F_HID + p * 8;
    *(float4*)&a[base]     = make_float4(acc[0][0], acc[0][1], acc[0][2], acc[0][3]);
    *(float4*)&a[base + 4] = make_float4(acc[0][4], acc[0][5], acc[0][6], acc[0][7]);
    *(float4*)&b[base]     = make_float4(acc[1][0], acc[1][1], acc[1][2], acc[1][3]);
    *(float4*)&b[base + 4] = make_float4(acc[1][4], acc[1][5], acc[1][6], acc[1][7]);
    *(float4*)&c[base]     = make_float4(acc[2][0], acc[2][1], acc[2][2], acc[2][3]);
    *(float4*)&c[base + 4] = make_float4(acc[2][4], acc[2][5], acc[2][6], acc[2][7]);
}

// ---------------- histogram of dst into cnt (=cursor storage) ----------------
__global__ __launch_bounds__(256) void hist_kernel(
    const int* __restrict__ ei, unsigned int* __restrict__ cnt)
{
    const int e = blockIdx.x * 256 + threadIdx.x;
    if (e >= N_EDGES) return;
    atomicAdd(&cnt[ei[N_EDGES + e]], 1u);
}

// ---------------- scan stage 1: block-local exclusive scan ----------------
__global__ __launch_bounds__(256) void scan_local_kernel(
    const unsigned int* __restrict__ cnt, unsigned int* __restrict__ off,
    unsigned int* __restrict__ partials)
{
    __shared__ unsigned int s[256];
    const int tid  = threadIdx.x;
    const int base = blockIdx.x * SCAN_CHUNK + tid * 8;

    unsigned int v[8];
    unsigned int tot = 0;
#pragma unroll
    for (int j = 0; j < 8; ++j) {
        unsigned int xv = (base + j < N_NODES) ? cnt[base + j] : 0u;
        v[j] = tot;
        tot += xv;
    }
    s[tid] = tot;
    __syncthreads();
    for (int d = 1; d < 256; d <<= 1) {
        unsigned int t_ = (tid >= d) ? s[tid - d] : 0u;
        __syncthreads();
        s[tid] += t_;
        __syncthreads();
    }
    const unsigned int excl = s[tid] - tot;
#pragma unroll
    for (int j = 0; j < 8; ++j)
        if (base + j < N_NODES) off[base + j] = excl + v[j];
    if (tid == 255) partials[blockIdx.x] = s[255];
}

// ---------------- scan stage 2: exclusive scan of block partials ----------------
__global__ void scan_partials_kernel(unsigned int* __restrict__ partials)
{
    if (threadIdx.x == 0 && blockIdx.x == 0) {
        unsigned int run = 0;
        for (int i = 0; i < NSCAN; ++i) {
            unsigned int t = partials[i];
            partials[i] = run;
            run += t;
        }
    }
}

// ---------------- scan stage 3: add block offsets; init cursor ----------------
__global__ __launch_bounds__(256) void scan_add_kernel(
    unsigned int* __restrict__ off, const unsigned int* __restrict__ partials,
    unsigned int* __restrict__ cursor)
{
    const int i = blockIdx.x * 256 + threadIdx.x;
    if (i >= N_NODES) return;
    const unsigned int o = off[i] + partials[i >> 11];   // i / SCAN_CHUNK
    off[i] = o;
    cursor[i] = o;
}

// ---------------- scatter edges into dst-grouped order ----------------
__global__ __launch_bounds__(256) void scatter_kernel(
    const int* __restrict__ ei, const float* __restrict__ ea,
    unsigned int* __restrict__ cursor, uint2* __restrict__ packed)
{
    const int e = blockIdx.x * 256 + threadIdx.x;
    if (e >= N_EDGES) return;
    const int src = ei[e];
    const int dst = ei[N_EDGES + e];
    const float ew = ea[e];
    const unsigned int pos = atomicAdd(&cursor[dst], 1u);
    packed[pos] = make_uint2((unsigned int)src, __float_as_uint(ew));
}

// ---------------- gather: c[n] -= sum ew*b[src]; degw[n] = sum ew ----------------
// 4 threads per node, 8 features each. cursor[n] now holds the group END.
__global__ __launch_bounds__(256) void gather_kernel(
    const uint2* __restrict__ packed,
    const unsigned int* __restrict__ off, const unsigned int* __restrict__ endo,
    const float* __restrict__ b,
    float* __restrict__ c, float* __restrict__ degw)
{
    const long long t = (long long)blockIdx.x * 256 + threadIdx.x;
    const int node = (int)(t >> 2);
    const int p    = (int)(t & 3);
    if (node >= N_NODES) return;

    const unsigned int s0 = off[node];
    const unsigned int e0 = endo[node];

    float4 acc0 = make_float4(0.f, 0.f, 0.f, 0.f);
    float4 acc1 = make_float4(0.f, 0.f, 0.f, 0.f);
    float dw = 0.f;

    for (unsigned int u = s0; u < e0; ++u) {
        const uint2 pe = packed[u];
        const float ew = __uint_as_float(pe.y);
        const float4* bs = (const float4*)(b + (size_t)pe.x * F_HID) + p * 2;
        float4 v0 = bs[0], v1 = bs[1];
        acc0.x += ew * v0.x; acc0.y += ew * v0.y;
        acc0.z += ew * v0.z; acc0.w += ew * v0.w;
        acc1.x += ew * v1.x; acc1.y += ew * v1.y;
        acc1.z += ew * v1.z; acc1.w += ew * v1.w;
        dw += ew;
    }

    float4* cd = (float4*)(c + (size_t)node * F_HID + p * 8);
    float4 c0 = cd[0], c1 = cd[1];
    c0.x -= acc0.x; c0.y -= acc0.y; c0.z -= acc0.z; c0.w -= acc0.w;
    c1.x -= acc1.x; c1.y -= acc1.y; c1.z -= acc1.z; c1.w -= acc1.w;
    cd[0] = c0; cd[1] = c1;
    if (p == 0) degw[node] = dw;
}

// ---------------- fallback: direct atomic edge scatter (round-1 path) ----------------
__global__ __launch_bounds__(256) void edge_scatter_kernel(
    const int* __restrict__ ei, const float* __restrict__ ea,
    const float* __restrict__ b,
    float* __restrict__ c, float* __restrict__ degw)
{
    const long long t = (long long)blockIdx.x * 256 + threadIdx.x;
    const int e = (int)(t >> 2);
    const int p = (int)(t & 3);
    if (e >= N_EDGES) return;

    const int src = ei[e];
    const int dst = ei[N_EDGES + e];
    const float ew = ea[e];

    const float4* bs = (const float4*)(b + (size_t)src * F_HID) + p * 2;
    float4 v0 = bs[0], v1 = bs[1];

    float* cd = c + (size_t)dst * F_HID + p * 8;
    unsafeAtomicAdd(&cd[0], -ew * v0.x);
    unsafeAtomicAdd(&cd[1], -ew * v0.y);
    unsafeAtomicAdd(&cd[2], -ew * v0.z);
    unsafeAtomicAdd(&cd[3], -ew * v0.w);
    unsafeAtomicAdd(&cd[4], -ew * v1.x);
    unsafeAtomicAdd(&cd[5], -ew * v1.y);
    unsafeAtomicAdd(&cd[6], -ew * v1.z);
    unsafeAtomicAdd(&cd[7], -ew * v1.w);
    if (p == 0) unsafeAtomicAdd(&degw[dst], ew);
}

// ---------------- finalize ----------------
__global__ __launch_bounds__(256) void finalize_kernel(
    const float* __restrict__ a, const float* __restrict__ c,
    const float* __restrict__ degw,
    const float* __restrict__ fc_w, const float* __restrict__ fc_b,
    float* __restrict__ out)
{
    __shared__ float Wf[N_CLS][F_HID];
    __shared__ float Bf[N_CLS];
    const int tid = threadIdx.x;
    for (int i = tid; i < N_CLS * F_HID; i += 256)
        ((float*)Wf)[i] = fc_w[i];
    if (tid < N_CLS) Bf[tid] = fc_b[tid];
    __syncthreads();

    const int n = blockIdx.x * 256 + tid;
    if (n >= N_NODES) return;

    const float dw = degw[n];
    const float4* av = (const float4*)(a + (size_t)n * F_HID);
    const float4* cv = (const float4*)(c + (size_t)n * F_HID);

    float h[F_HID];
#pragma unroll
    for (int i = 0; i < F_HID / 4; ++i) {
        float4 A = av[i], C = cv[i];
        float t0 = C.x + dw * A.x;
        float t1 = C.y + dw * A.y;
        float t2 = C.z + dw * A.z;
        float t3 = C.w + dw * A.w;
        h[4 * i + 0] = t0 > 0.f ? t0 : expm1f(t0);
        h[4 * i + 1] = t1 > 0.f ? t1 : expm1f(t1);
        h[4 * i + 2] = t2 > 0.f ? t2 : expm1f(t2);
        h[4 * i + 3] = t3 > 0.f ? t3 : expm1f(t3);
    }

    float logits[N_CLS];
    float mx = -1e30f;
#pragma unroll
    for (int j = 0; j < N_CLS; ++j) {
        float s = Bf[j];
#pragma unroll
        for (int f = 0; f < F_HID; ++f) s += h[f] * Wf[j][f];
        logits[j] = s;
        mx = fmaxf(mx, s);
    }
    float sum = 0.f;
#pragma unroll
    for (int j = 0; j < N_CLS; ++j) sum += expf(logits[j] - mx);
    const float lse = mx + logf(sum);

    float* o = out + (size_t)n * N_CLS;
#pragma unroll
    for (int j = 0; j < N_CLS; ++j) o[j] = logits[j] - lse;
}

extern "C" void kernel_launch(void* const* d_in, const int* in_sizes, int n_in,
                              void* d_out, int out_size, void* d_ws, size_t ws_size,
                              hipStream_t stream) {
    const float* x   = (const float*)d_in[0];
    const int*   ei  = (const int*)d_in[1];
    const float* ea  = (const float*)d_in[2];
    const float* W1  = (const float*)d_in[3];
    const float* b1  = (const float*)d_in[4];
    const float* W2  = (const float*)d_in[5];
    const float* W3  = (const float*)d_in[6];
    const float* b3  = (const float*)d_in[7];
    const float* fcw = (const float*)d_in[8];
    const float* fcb = (const float*)d_in[9];
    float* out = (float*)d_out;

    const size_t NF = (size_t)N_NODES * F_HID;
    float* a    = (float*)d_ws;
    float* b    = a + NF;
    float* c    = b + NF;
    float* degw = c + NF;
    unsigned int* off     = (unsigned int*)(degw + N_NODES);
    unsigned int* cursor  = off + N_NODES;
    unsigned int* partials= cursor + N_NODES;
    uint2* packed = (uint2*)(partials + 64);        // 8B-aligned (all prior counts even)

    const size_t need = ((size_t)(3 * NF + 3 * N_NODES + 64)) * 4
                      + (size_t)N_EDGES * 8;

    gemm3_kernel<<<(N_NODES + 63) / 64, 256, 0, stream>>>(
        x, W1, b1, W2, W3, b3, a, b, c);

    if (ws_size >= need) {
        // counting-sort-by-dst + gather path (no fp32 atomics)
        hipMemsetAsync(cursor, 0, N_NODES * sizeof(unsigned int), stream);
        hist_kernel<<<(N_EDGES + 255) / 256, 256, 0, stream>>>(ei, cursor);
        scan_local_kernel<<<NSCAN, 256, 0, stream>>>(cursor, off, partials);
        scan_partials_kernel<<<1, 64, 0, stream>>>(partials);
        scan_add_kernel<<<(N_NODES + 255) / 256, 256, 0, stream>>>(off, partials, cursor);
        scatter_kernel<<<(N_EDGES + 255) / 256, 256, 0, stream>>>(ei, ea, cursor, packed);
        gather_kernel<<<(int)(((long long)N_NODES * 4 + 255) / 256), 256, 0, stream>>>(
            packed, off, cursor, b, c, degw);
    } else {
        // fallback: direct atomic scatter
        hipMemsetAsync(degw, 0, N_NODES * sizeof(float), stream);
        edge_scatter_kernel<<<(int)(((long long)N_EDGES * 4 + 255) / 256), 256, 0, stream>>>(
            ei, ea, b, c, degw);
    }

    finalize_kernel<<<(N_NODES + 255) / 256, 256, 0, stream>>>(
        a, c, degw, fcw, fcb, out);
}